// Round 6
// baseline (62.015 us; speedup 1.0000x reference)
//
#include <hip/hip_runtime.h>
#include <math.h>

// DisCo (distance correlation) for N=8192, scalar output. THREE kernels:
//   K1 k_pass1 (2048): block owns 4 rows; 4 waves split columns, LDS-combine ->
//       full row sums; writes avga/avgb[i] and per-block dbl partial gpa/gpb
//       (sum_i w_i * rowsum_i) for the grand mean.
//   K2 k_pass2 (2048): prologue reduces gpa/gpb -> ha=ga/2,hb; body sweeps full
//       rows (5 streams, wr_j/ws_j on the fly); LDS-combine -> complete per-row
//       Q=Σw d e, P1a=Σ(wr)d, P2=Σ(ws)d, P3=Σ(wr)e, P1b=Σ(ws)e (double out).
//   K3 k_fin (1x1024): 10 O(N) scalars; per-row T_AB/T_AA/T_BB assembly;
//       final reduce + power branch + NaN/clamp.
// Algebra (validated R5, absmax 0.0): A_ij = d_ij - r_i - r_j, d=|a_i-a_j|,
// r=avg-ga/2; polynomial terms are O(N); only |.|-terms swept pairwise.
// No atomics, no fences (R4 lesson: per-block __threadfence ~ +125us/kernel).
// All reductions fixed-order -> deterministic.

#define NN 8192
#define BLK 256
#define NWAVE 4                         // waves per block (split columns)
#define RPB 4                           // rows per block (shared by all waves)
#define GRIDP (NN / RPB)                // 2048 blocks
#define SEGC (NN / NWAVE)               // 2048 columns per wave
#define ITERS (SEGC / 256)              // 8 float4-iters (64 lanes x 4)

// ---------------------------------------------------------------- K1: pass 1
__global__ __launch_bounds__(BLK) void k_pass1(
    const float* __restrict__ a, const float* __restrict__ b,
    const float* __restrict__ w,
    float* __restrict__ avga, float* __restrict__ avgb,
    double* __restrict__ gpa, double* __restrict__ gpb) {
  const int lane = threadIdx.x & 63;
  const int wv = threadIdx.x >> 6;
  const int i0 = blockIdx.x * RPB;

  float ai[RPB], bi[RPB], sa[RPB], sb[RPB];
#pragma unroll
  for (int m = 0; m < RPB; ++m) {
    ai[m] = a[i0 + m]; bi[m] = b[i0 + m];
    sa[m] = 0.f; sb[m] = 0.f;
  }

  const int jb = wv * SEGC;
  const float4* a4 = (const float4*)(a + jb) + lane;
  const float4* b4 = (const float4*)(b + jb) + lane;
  const float4* w4 = (const float4*)(w + jb) + lane;

#pragma unroll 1
  for (int k = 0; k < ITERS; ++k) {
    const int ix = k * 64;
    const float4 A = a4[ix], B = b4[ix], Wt = w4[ix];
#define P1E(e)                                              \
    {                                                       \
      _Pragma("unroll")                                     \
      for (int m = 0; m < RPB; ++m) {                       \
        sa[m] = fmaf(fabsf(ai[m] - A.e), Wt.e, sa[m]);      \
        sb[m] = fmaf(fabsf(bi[m] - B.e), Wt.e, sb[m]);      \
      }                                                     \
    }
    P1E(x) P1E(y) P1E(z) P1E(w)
#undef P1E
  }

#pragma unroll
  for (int off = 32; off >= 1; off >>= 1) {
#pragma unroll
    for (int m = 0; m < RPB; ++m) {
      sa[m] += __shfl_xor(sa[m], off);
      sb[m] += __shfl_xor(sb[m], off);
    }
  }

  __shared__ float lsa[NWAVE][RPB], lsb[NWAVE][RPB];
  if (lane == 0) {
#pragma unroll
    for (int m = 0; m < RPB; ++m) { lsa[wv][m] = sa[m]; lsb[wv][m] = sb[m]; }
  }
  __syncthreads();
  if (threadIdx.x == 0) {
    double ga = 0.0, gb = 0.0;
#pragma unroll
    for (int m = 0; m < RPB; ++m) {
      const double rowA = (double)lsa[0][m] + lsa[1][m] + lsa[2][m] + lsa[3][m];
      const double rowB = (double)lsb[0][m] + lsb[1][m] + lsb[2][m] + lsb[3][m];
      avga[i0 + m] = (float)(rowA * (1.0 / NN));
      avgb[i0 + m] = (float)(rowB * (1.0 / NN));
      const double wi = (double)w[i0 + m];
      ga += wi * rowA;
      gb += wi * rowB;
    }
    gpa[blockIdx.x] = ga;
    gpb[blockIdx.x] = gb;
  }
}

// ---------------------------------------------------------------- K2: pass 2
__global__ __launch_bounds__(BLK) void k_pass2(
    const float* __restrict__ a, const float* __restrict__ b,
    const float* __restrict__ w,
    const float* __restrict__ avga, const float* __restrict__ avgb,
    const double* __restrict__ gpa, const double* __restrict__ gpb,
    double* __restrict__ Qd, double* __restrict__ P1ad, double* __restrict__ P2d,
    double* __restrict__ P3d, double* __restrict__ P1bd) {
  const int lane = threadIdx.x & 63;
  const int wv = threadIdx.x >> 6;
  const int i0 = blockIdx.x * RPB;

  // prologue: ha = ga/2, hb = gb/2 from 2048 double partials (fixed order)
  double da = 0.0, db = 0.0;
#pragma unroll
  for (int k = 0; k < GRIDP / BLK; ++k) {
    const int t = threadIdx.x + k * BLK;
    da += gpa[t]; db += gpb[t];
  }
#pragma unroll
  for (int off = 32; off >= 1; off >>= 1) {
    da += __shfl_xor(da, off);
    db += __shfl_xor(db, off);
  }
  __shared__ double lg[2][NWAVE];
  if (lane == 0) { lg[0][wv] = da; lg[1][wv] = db; }
  __syncthreads();
  const double n2 = (double)NN * (double)NN;
  const float ha = (float)(0.5 * (lg[0][0] + lg[0][1] + lg[0][2] + lg[0][3]) / n2);
  const float hb = (float)(0.5 * (lg[1][0] + lg[1][1] + lg[1][2] + lg[1][3]) / n2);

  float ai[RPB], bi[RPB];
  float q[RPB], g1a[RPB], g2[RPB], g3[RPB], g1b[RPB];
#pragma unroll
  for (int m = 0; m < RPB; ++m) {
    ai[m] = a[i0 + m]; bi[m] = b[i0 + m];
    q[m] = 0.f; g1a[m] = 0.f; g2[m] = 0.f; g3[m] = 0.f; g1b[m] = 0.f;
  }

  const int jb = wv * SEGC;
  const float4* a4 = (const float4*)(a + jb)    + lane;
  const float4* b4 = (const float4*)(b + jb)    + lane;
  const float4* w4 = (const float4*)(w + jb)    + lane;
  const float4* c4 = (const float4*)(avga + jb) + lane;
  const float4* d4 = (const float4*)(avgb + jb) + lane;

#pragma unroll 1
  for (int k = 0; k < ITERS; ++k) {
    const int ix = k * 64;
    const float4 A = a4[ix], B = b4[ix], Wt = w4[ix], CA = c4[ix], CB = d4[ix];
#define P2E(e)                                              \
    {                                                       \
      const float wr = Wt.e * (CA.e - ha);                  \
      const float ws = Wt.e * (CB.e - hb);                  \
      _Pragma("unroll")                                     \
      for (int m = 0; m < RPB; ++m) {                       \
        const float dd = fabsf(ai[m] - A.e);                \
        const float ee = fabsf(bi[m] - B.e);                \
        g1a[m] = fmaf(wr, dd, g1a[m]);                      \
        g2[m]  = fmaf(ws, dd, g2[m]);                       \
        g3[m]  = fmaf(wr, ee, g3[m]);                       \
        g1b[m] = fmaf(ws, ee, g1b[m]);                      \
        q[m]   = fmaf(Wt.e * dd, ee, q[m]);                 \
      }                                                     \
    }
    P2E(x) P2E(y) P2E(z) P2E(w)
#undef P2E
  }

#pragma unroll
  for (int off = 32; off >= 1; off >>= 1) {
#pragma unroll
    for (int m = 0; m < RPB; ++m) {
      q[m]   += __shfl_xor(q[m], off);
      g1a[m] += __shfl_xor(g1a[m], off);
      g2[m]  += __shfl_xor(g2[m], off);
      g3[m]  += __shfl_xor(g3[m], off);
      g1b[m] += __shfl_xor(g1b[m], off);
    }
  }

  __shared__ float lq[NWAVE][5][RPB];
  if (lane == 0) {
#pragma unroll
    for (int m = 0; m < RPB; ++m) {
      lq[wv][0][m] = q[m];   lq[wv][1][m] = g1a[m]; lq[wv][2][m] = g2[m];
      lq[wv][3][m] = g3[m];  lq[wv][4][m] = g1b[m];
    }
  }
  __syncthreads();
  if (threadIdx.x < RPB) {
    const int m = threadIdx.x;
    const int i = i0 + m;
    Qd[i]   = (double)lq[0][0][m] + lq[1][0][m] + lq[2][0][m] + lq[3][0][m];
    P1ad[i] = (double)lq[0][1][m] + lq[1][1][m] + lq[2][1][m] + lq[3][1][m];
    P2d[i]  = (double)lq[0][2][m] + lq[1][2][m] + lq[2][2][m] + lq[3][2][m];
    P3d[i]  = (double)lq[0][3][m] + lq[1][3][m] + lq[2][3][m] + lq[3][3][m];
    P1bd[i] = (double)lq[0][4][m] + lq[1][4][m] + lq[2][4][m] + lq[3][4][m];
  }
}

// ------------------------------- K3: scalars + per-row assembly + final scalar
#define BLKF 1024
__global__ __launch_bounds__(BLKF) void k_fin(
    const float* __restrict__ a, const float* __restrict__ b,
    const float* __restrict__ w,
    const float* __restrict__ avga, const float* __restrict__ avgb,
    const double* __restrict__ gpa, const double* __restrict__ gpb,
    const double* __restrict__ Qd, const double* __restrict__ P1ad,
    const double* __restrict__ P2d, const double* __restrict__ P3d,
    const double* __restrict__ P1bd,
    const int* __restrict__ powerPtr, float* __restrict__ out) {
  const int lane = threadIdx.x & 63;
  const int wvf = threadIdx.x >> 6;   // 16 waves
  const double n2 = (double)NN * (double)NN;

  // ---- ha/hb from gp partials
  double da = 0.0, db = 0.0;
#pragma unroll
  for (int k = 0; k < GRIDP / BLKF; ++k) {
    const int t = threadIdx.x + k * BLKF;
    da += gpa[t]; db += gpb[t];
  }
#pragma unroll
  for (int off = 32; off >= 1; off >>= 1) {
    da += __shfl_xor(da, off);
    db += __shfl_xor(db, off);
  }
  __shared__ double lg[2][16];
  __shared__ float hsh[2];
  if (lane == 0) { lg[0][wvf] = da; lg[1][wvf] = db; }
  __syncthreads();
  if (threadIdx.x == 0) {
    double ga = 0.0, gb = 0.0;
    for (int t = 0; t < 16; ++t) { ga += lg[0][t]; gb += lg[1][t]; }
    hsh[0] = (float)(0.5 * ga / n2);
    hsh[1] = (float)(0.5 * gb / n2);
  }
  __syncthreads();
  const float ha = hsh[0], hb = hsh[1];

  // ---- 10 global scalars
  double p[10];
#pragma unroll
  for (int t = 0; t < 10; ++t) p[t] = 0.0;
  for (int k = 0; k < NN / BLKF; ++k) {
    const int i = threadIdx.x + k * BLKF;
    const double wi = (double)w[i];
    const double aiv = (double)a[i], biv = (double)b[i];
    const double ri = (double)(avga[i] - ha);
    const double si = (double)(avgb[i] - hb);
    p[0] += wi;
    p[1] += wi * aiv;
    p[2] += wi * aiv * aiv;
    p[3] += wi * biv;
    p[4] += wi * biv * biv;
    p[5] += wi * ri;
    p[6] += wi * si;
    p[7] += wi * ri * ri;
    p[8] += wi * si * si;
    p[9] += wi * ri * si;
  }
#pragma unroll
  for (int off = 32; off >= 1; off >>= 1) {
#pragma unroll
    for (int t = 0; t < 10; ++t) p[t] += __shfl_xor(p[t], off);
  }
  __shared__ double lp[10][16];
  __shared__ double sc[10];
  if (lane == 0) {
#pragma unroll
    for (int t = 0; t < 10; ++t) lp[t][wvf] = p[t];
  }
  __syncthreads();
  if (threadIdx.x < 10) {
    double s = 0.0;
    for (int t = 0; t < 16; ++t) s += lp[threadIdx.x][t];
    sc[threadIdx.x] = s;
  }
  __syncthreads();
  const double W   = sc[0], Ma1 = sc[1], Ma2 = sc[2], Mb1 = sc[3], Mb2 = sc[4];
  const double Swr = sc[5], Sws = sc[6], Swr2 = sc[7], Sws2 = sc[8], Swrs = sc[9];

  // ---- per-row T assembly + weighted reduce
  double ab = 0.0, aa = 0.0, bb = 0.0;
  for (int k = 0; k < NN / BLKF; ++k) {
    const int i = threadIdx.x + k * BLKF;
    const double Qi = Qd[i], P1A = P1ad[i], P2v = P2d[i], P3v = P3d[i], P1B = P1bd[i];
    const double av = (double)avga[i], bv = (double)avgb[i];
    const double ri = (double)(avga[i] - ha);
    const double si = (double)(avgb[i] - hb);
    const double aiv = (double)a[i], biv = (double)b[i], wi = (double)w[i];
    const double P0a = av * (double)NN;
    const double P0b = bv * (double)NN;

    const double TAB = Qi - si * P0a - P2v - ri * P0b - P3v
                     + ri * si * W + ri * Sws + si * Swr + Swrs;
    const double TAA = (aiv * aiv * W - 2.0 * aiv * Ma1 + Ma2)
                     - 2.0 * ri * P0a - 2.0 * P1A
                     + ri * ri * W + 2.0 * ri * Swr + Swr2;
    const double TBB = (biv * biv * W - 2.0 * biv * Mb1 + Mb2)
                     - 2.0 * si * P0b - 2.0 * P1B
                     + si * si * W + 2.0 * si * Sws + Sws2;

    ab += fabs(TAB) * wi;
    aa += TAA * wi;
    bb += TBB * wi;
  }
#pragma unroll
  for (int off = 32; off >= 1; off >>= 1) {
    ab += __shfl_xor(ab, off);
    aa += __shfl_xor(aa, off);
    bb += __shfl_xor(bb, off);
  }
  __shared__ double l[3][16];
  if (lane == 0) { l[0][wvf] = ab; l[1][wvf] = aa; l[2][wvf] = bb; }
  __syncthreads();
  if (threadIdx.x == 0) {
    double sab = 0.0, saa = 0.0, sbb = 0.0;
    for (int t = 0; t < 16; ++t) { sab += l[0][t]; saa += l[1][t]; sbb += l[2][t]; }
    const double num = sab / n2;
    const double mAA = saa / n2;
    const double mBB = sbb / n2;
    const double den = fabs(mAA * mBB);
    const int pw = powerPtr[0];
    double d;
    if (pw == 1) {
      d = num / sqrt(den + 1e-12);
    } else if (pw == 2) {
      d = (num * num) / (den + 1e-12);
    } else {
      d = pow(num / sqrt(mAA * mBB) + 1e-12, (double)pw);
    }
    if (isnan(d)) d = 0.0;
    if (d < 0.0) d = 0.0;
    out[0] = (float)d;
  }
}

// -------------------------------------------------------------------- launcher
extern "C" void kernel_launch(void* const* d_in, const int* in_sizes, int n_in,
                              void* d_out, int out_size, void* d_ws, size_t ws_size,
                              hipStream_t stream) {
  const float* a = (const float*)d_in[0];
  const float* b = (const float*)d_in[1];
  const float* w = (const float*)d_in[2];
  const int* power = (const int*)d_in[3];
  float* out = (float*)d_out;

  double* dws = (double*)d_ws;        // 8B-aligned base
  double* Qd   = dws;                 // [N]
  double* P1ad = Qd + NN;             // [N]
  double* P2d  = P1ad + NN;           // [N]
  double* P3d  = P2d + NN;            // [N]
  double* P1bd = P3d + NN;            // [N]
  double* gpa  = P1bd + NN;           // [GRIDP]
  double* gpb  = gpa + GRIDP;         // [GRIDP]
  float* avga  = (float*)(gpb + GRIDP);  // [N]
  float* avgb  = avga + NN;              // [N]

  k_pass1<<<GRIDP, BLK, 0, stream>>>(a, b, w, avga, avgb, gpa, gpb);
  k_pass2<<<GRIDP, BLK, 0, stream>>>(a, b, w, avga, avgb, gpa, gpb,
                                     Qd, P1ad, P2d, P3d, P1bd);
  k_fin<<<1, BLKF, 0, stream>>>(a, b, w, avga, avgb, gpa, gpb,
                                Qd, P1ad, P2d, P3d, P1bd, power, out);
}